// Round 1
// baseline (415.302 us; speedup 1.0000x reference)
//
#include <hip/hip_runtime.h>

#define D      256      // D_IN == D_OUT
#define NNODES 50000
#define KNBR   32

// ---------------------------------------------------------------------------
// Kernel 1: h[n][o] = sum_i x[n][i] * W[o][i]   (both row-major, K contiguous)
// BM=BN=BK=64, 256 threads, 4x4 microtile (strided), float4 LDS reads.
// ---------------------------------------------------------------------------
#define BM 64
#define BN 64
#define BK 64
#define PADF 68   // padded LDS row stride in floats (64 data + 4 pad)

__global__ __launch_bounds__(256, 2)
void gemm_xwT(const float* __restrict__ x, const float* __restrict__ W,
              float* __restrict__ h) {
  __shared__ float xs[BM * PADF];
  __shared__ float ws[BN * PADF];

  const int tid  = threadIdx.x;
  const int tx   = tid & 15;    // col group 0..15
  const int ty   = tid >> 4;    // row group 0..15
  const int brow = blockIdx.x * BM;
  const int bcol = blockIdx.y * BN;

  float acc[4][4];
#pragma unroll
  for (int i = 0; i < 4; i++)
#pragma unroll
    for (int j = 0; j < 4; j++) acc[i][j] = 0.f;

  for (int k0 = 0; k0 < D; k0 += BK) {
    // stage: 64 rows x 16 float4 each for x-tile and W-tile
#pragma unroll
    for (int q = 0; q < 4; q++) {
      int f  = tid + q * 256;   // flat float4 index 0..1023
      int r  = f >> 4;          // 16 float4 per row
      int c4 = f & 15;
      int grow = brow + r;
      int srow = grow < NNODES ? grow : NNODES - 1;  // clamp tail rows
      float4 xv = *reinterpret_cast<const float4*>(&x[srow * D + k0 + c4 * 4]);
      *reinterpret_cast<float4*>(&xs[r * PADF + c4 * 4]) = xv;
      float4 wv = *reinterpret_cast<const float4*>(&W[(bcol + r) * D + k0 + c4 * 4]);
      *reinterpret_cast<float4*>(&ws[r * PADF + c4 * 4]) = wv;
    }
    __syncthreads();

#pragma unroll
    for (int kk = 0; kk < BK; kk += 4) {
      float4 a[4], b[4];
#pragma unroll
      for (int i = 0; i < 4; i++)
        a[i] = *reinterpret_cast<const float4*>(&xs[(ty + 16 * i) * PADF + kk]);
#pragma unroll
      for (int j = 0; j < 4; j++)
        b[j] = *reinterpret_cast<const float4*>(&ws[(tx + 16 * j) * PADF + kk]);
#pragma unroll
      for (int i = 0; i < 4; i++)
#pragma unroll
        for (int j = 0; j < 4; j++) {
          acc[i][j] += a[i].x * b[j].x;
          acc[i][j] += a[i].y * b[j].y;
          acc[i][j] += a[i].z * b[j].z;
          acc[i][j] += a[i].w * b[j].w;
        }
    }
    __syncthreads();
  }

#pragma unroll
  for (int i = 0; i < 4; i++) {
    int grow = brow + ty + 16 * i;
    if (grow < NNODES) {
#pragma unroll
      for (int j = 0; j < 4; j++)
        h[grow * D + bcol + tx + 16 * j] = acc[i][j];
    }
  }
}

// ---------------------------------------------------------------------------
// Kernel 2: per node n (block), per channel o (thread): gather 32 values of
// h[nbr][o], Batcher odd-even mergesort (191 CE), mean of ranks 14..17.
// ---------------------------------------------------------------------------

// One (P,K) pass of Batcher odd-even mergesort over 32 elements, ascending.
template <int P, int K>
__device__ __forceinline__ void oem_pass(float* v) {
#pragma unroll
  for (int j = K % P; j + K < 32; j += 2 * K) {
#pragma unroll
    for (int i = 0; i < K; i++) {
      if (i + j + K < 32 && ((i + j) / (2 * P) == (i + j + K) / (2 * P))) {
        float lo = fminf(v[i + j], v[i + j + K]);
        float hi = fmaxf(v[i + j], v[i + j + K]);
        v[i + j] = lo;
        v[i + j + K] = hi;
      }
    }
  }
}

__device__ __forceinline__ void sort32(float* v) {
  oem_pass<1, 1>(v);
  oem_pass<2, 2>(v);  oem_pass<2, 1>(v);
  oem_pass<4, 4>(v);  oem_pass<4, 2>(v);  oem_pass<4, 1>(v);
  oem_pass<8, 8>(v);  oem_pass<8, 4>(v);  oem_pass<8, 2>(v);  oem_pass<8, 1>(v);
  oem_pass<16, 16>(v); oem_pass<16, 8>(v); oem_pass<16, 4>(v);
  oem_pass<16, 2>(v);  oem_pass<16, 1>(v);
}

__global__ __launch_bounds__(256, 4)
void trimmed_gather(const float* __restrict__ h, const int* __restrict__ nbrs,
                    float* __restrict__ out) {
  const int n = blockIdx.x;
  const int o = threadIdx.x;

  float v[KNBR];
#pragma unroll
  for (int k = 0; k < KNBR; k++) {
    int r = nbrs[n * KNBR + k];       // block-uniform -> scalar load
    v[k] = h[r * D + o];              // coalesced: 256 threads x 4B
  }

  sort32(v);

  out[n * D + o] = (v[14] + v[15] + v[16] + v[17]) * 0.25f;
}

// ---------------------------------------------------------------------------
extern "C" void kernel_launch(void* const* d_in, const int* in_sizes, int n_in,
                              void* d_out, int out_size, void* d_ws, size_t ws_size,
                              hipStream_t stream) {
  const float* x    = (const float*)d_in[0];
  const int*   nbrs = (const int*)d_in[1];
  const float* W    = (const float*)d_in[2];
  float*       out  = (float*)d_out;
  float*       h    = (float*)d_ws;   // 50000*256*4 = 51.2 MB scratch

  dim3 g1((NNODES + BM - 1) / BM, D / BN);
  gemm_xwT<<<g1, dim3(256), 0, stream>>>(x, W, h);
  trimmed_gather<<<dim3(NNODES), dim3(256), 0, stream>>>(h, nbrs, out);
}